// Round 3
// baseline (2602.637 us; speedup 1.0000x reference)
//
#include <hip/hip_runtime.h>
#include <hip/hip_bf16.h>

// MPNN GNN: V nodes (feat 32), E edges (feat 16), H=32, 6 message-passing steps.
// Factorization: W_e = relu(ef@e_w1)@e_w2 is rank-128 in the edge-hidden dim:
//   msg[e,o] = sum_k a[e,k] * T[src[e], k*32+o] + Tb[src[e], o]
// with a = relu(ef@e_w1+e_b1)  (E x 128, loop-invariant, f32)
//      T[v,k,o] = sum_i h[v,i]*e_w2[k*1024+i*32+o]   (NEVER materialized in HBM:
//      computed per-block in LDS, f32, fused with the edge message+scatter)
// R1: bf16 T storage -> absmax 0.31 (fail). R2: f32 global T -> d_ws overflow (crash).
// R3: fused LDS T, all-f32, workspace ~107 MB.

#define NB 8  // src nodes per block

// ---------------- node projection: h = relu(nf@w1+b1)@w2+b2 ----------------
__global__ void k_proj(const float* __restrict__ nf, const float* __restrict__ w1,
                       const float* __restrict__ b1, const float* __restrict__ w2,
                       const float* __restrict__ b2, float* __restrict__ hseq, int nV) {
  __shared__ float sw1[1024], sw2[1024], sb1[32], sb2[32];
  int t = threadIdx.x;
  for (int i = t; i < 1024; i += 256) { sw1[i] = w1[i]; sw2[i] = w2[i]; }
  if (t < 32) { sb1[t] = b1[t]; sb2[t] = b2[t]; }
  __syncthreads();
  int v = blockIdx.x * 256 + t;
  if (v >= nV) return;
  float x[32], t1[32];
#pragma unroll
  for (int i = 0; i < 32; i++) x[i] = nf[(size_t)v * 32 + i];
#pragma unroll
  for (int j = 0; j < 32; j++) {
    float s = sb1[j];
#pragma unroll
    for (int i = 0; i < 32; i++) s += x[i] * sw1[i * 32 + j];
    t1[j] = fmaxf(s, 0.f);
  }
#pragma unroll
  for (int j = 0; j < 32; j++) {
    float s = sb2[j];
#pragma unroll
    for (int i = 0; i < 32; i++) s += t1[i] * sw2[i * 32 + j];
    hseq[(size_t)v * 32 + j] = s;
  }
}

// ---------------- edge hidden: a = relu(ef@e_w1+e_b1), (E x 128) f32 -------
__global__ void k_edgeh(const float* __restrict__ ef, const float* __restrict__ w1,
                        const float* __restrict__ b1, float* __restrict__ a, int nE) {
  __shared__ float sw1[16 * 128], sb1[128], sef[2 * 16];
  int t = threadIdx.x;
  for (int i = t; i < 2048; i += 256) sw1[i] = w1[i];
  if (t < 128) sb1[t] = b1[t];
  int e0 = blockIdx.x * 2;
  if (t < 32) {
    int e = e0 + (t >> 4);
    if (e < nE) sef[t] = ef[(size_t)e * 16 + (t & 15)];
  }
  __syncthreads();
  int el = t >> 7, c = t & 127;
  int e = e0 + el;
  if (e >= nE) return;
  float s = sb1[c];
#pragma unroll
  for (int i = 0; i < 16; i++) s += sef[el * 16 + i] * sw1[i * 128 + c];
  a[(size_t)e * 128 + c] = fmaxf(s, 0.f);
}

// ---------------- CSR by src ----------------
__global__ void k_count(const int* __restrict__ src, int* __restrict__ counts, int nE) {
  int e = blockIdx.x * 256 + threadIdx.x;
  if (e < nE) atomicAdd(&counts[src[e]], 1);
}

__global__ void k_scan(const int* __restrict__ counts, int* __restrict__ row_ptr, int nV) {
  __shared__ int buf[1024];
  __shared__ int s_off;
  int t = threadIdx.x;
  if (t == 0) s_off = 0;
  __syncthreads();
  for (int base = 0; base < nV; base += 1024) {
    int x = (base + t < nV) ? counts[base + t] : 0;
    buf[t] = x;
    __syncthreads();
    for (int d = 1; d < 1024; d <<= 1) {
      int v2 = (t >= d) ? buf[t - d] : 0;
      __syncthreads();
      buf[t] += v2;
      __syncthreads();
    }
    int incl = buf[t];
    int off = s_off;
    __syncthreads();
    if (base + t < nV) row_ptr[base + t] = off + incl - x;  // exclusive
    if (t == 1023) s_off = off + incl;
    __syncthreads();
  }
  if (t == 0) row_ptr[nV] = s_off;
}

__global__ void k_copy(const int* __restrict__ row_ptr, int* __restrict__ cursor, int nV) {
  int v = blockIdx.x * 256 + threadIdx.x;
  if (v < nV) cursor[v] = row_ptr[v];
}

__global__ void k_scatter(const int* __restrict__ src, int* __restrict__ cursor,
                          int* __restrict__ perm, int nE) {
  int e = blockIdx.x * 256 + threadIdx.x;
  if (e < nE) {
    int p = atomicAdd(&cursor[src[e]], 1);
    perm[p] = e;
  }
}

// ---------------- fused per-step: T-in-LDS + message + scatter -------------
// Block = (group of NB src nodes) x (k-chunk of 32 of the 128 edge-hidden dims).
// grid.x = ceil(nV/NB) * 4.  LDS: T subtile 8x32x32 f32 = 32 KB.
__global__ void k_step(const float* __restrict__ hseq, const float* __restrict__ w2,
                       const float* __restrict__ b2, const float* __restrict__ a,
                       const int* __restrict__ row_ptr, const int* __restrict__ perm,
                       const int* __restrict__ dst, float* __restrict__ agg, int nV) {
  __shared__ float sT[NB * 1024];  // [n][k][o], o fastest -> lane o hits bank o
  __shared__ float sh[NB][32];
  __shared__ float sTb[NB][32];
  __shared__ int s_rp[NB + 1];
  int t = threadIdx.x;
  int grp = blockIdx.x >> 2;
  int kc = blockIdx.x & 3;
  int v0 = grp * NB;
  if (t <= NB) {
    int v = v0 + t;
    if (v > nV) v = nV;
    s_rp[t] = row_ptr[v];
  }
  for (int i = t; i < NB * 32; i += 256) {
    int n = i >> 5, v = v0 + n;
    sh[n][i & 31] = (v < nV) ? hseq[(size_t)v * 32 + (i & 31)] : 0.f;
  }
  __syncthreads();
  if (s_rp[0] == s_rp[NB]) return;  // group has no out-edges (block-uniform)

  // T subtile: k in [kc*32, kc*32+32), all 8 nodes
  for (int idx = t; idx < 1024; idx += 256) {
    int k = idx >> 5, o = idx & 31;
    const float* w = w2 + (size_t)(kc * 32 + k) * 1024 + o;  // + i*32
    float acc[NB];
#pragma unroll
    for (int n = 0; n < NB; n++) acc[n] = 0.f;
#pragma unroll 8
    for (int i = 0; i < 32; i++) {
      float wv = w[i * 32];
#pragma unroll
      for (int n = 0; n < NB; n++) acc[n] += sh[n][i] * wv;
    }
#pragma unroll
    for (int n = 0; n < NB; n++) sT[(n << 10) + idx] = acc[n];
  }
  // Tb (edge-MLP bias term), added once by the kc==0 blocks
  if (kc == 0) {
    for (int idx = t; idx < NB * 32; idx += 256) {
      int n = idx >> 5, o = idx & 31;
      float s = 0.f;
#pragma unroll
      for (int i = 0; i < 32; i++) s += sh[n][i] * b2[i * 32 + o];
      sTb[n][o] = s;
    }
  }
  __syncthreads();

  int lane_o = t & 31, sub = t >> 5;  // 8 edge slots x 32 output lanes
  int beg = s_rp[0], end = s_rp[NB];
  for (int idx = beg + sub; idx < end; idx += 8) {
    int n = 0;
    while (idx >= s_rp[n + 1]) n++;  // which of the 8 nodes owns this edge
    int e = perm[idx];
    const float4* a4 = (const float4*)(a + (size_t)e * 128 + kc * 32);
    float s = (kc == 0) ? sTb[n][lane_o] : 0.f;
    const float* Tn = sT + (n << 10) + lane_o;
#pragma unroll
    for (int kq = 0; kq < 8; kq++) {
      float4 av = a4[kq];
      s += av.x * Tn[(kq * 4 + 0) << 5];
      s += av.y * Tn[(kq * 4 + 1) << 5];
      s += av.z * Tn[(kq * 4 + 2) << 5];
      s += av.w * Tn[(kq * 4 + 3) << 5];
    }
    atomicAdd(&agg[(size_t)dst[e] * 32 + lane_o], s);
  }
}

// ---------------- per-step GRU (single step), in-place on hseq -------------
__global__ void k_gru(const float* __restrict__ agg, const float* __restrict__ cbias,
                      const float* __restrict__ wih, const float* __restrict__ whh,
                      const float* __restrict__ bih, const float* __restrict__ bhh,
                      float* __restrict__ hseq, int nV) {
  __shared__ float swih[96 * 32], swhh[96 * 32], sbih[96], sbhh[96], scb[32];
  int t = threadIdx.x;
  for (int i = t; i < 3072; i += 256) { swih[i] = wih[i]; swhh[i] = whh[i]; }
  if (t < 96) { sbih[t] = bih[t]; sbhh[t] = bhh[t]; }
  if (t < 32) scb[t] = cbias[t];
  __syncthreads();
  int v = blockIdx.x * 256 + t;
  if (v >= nV) return;
  float x[32], hd[32];
#pragma unroll
  for (int i = 0; i < 32; i++) {
    x[i] = fmaxf(agg[(size_t)v * 32 + i] + scb[i], 0.f);
    hd[i] = hseq[(size_t)v * 32 + i];
  }
  float out[32];
#pragma unroll 4
  for (int o = 0; o < 32; o++) {
    float gir = sbih[o], ghr = sbhh[o];
    float giz = sbih[32 + o], ghz = sbhh[32 + o];
    float gin = sbih[64 + o], ghn = sbhh[64 + o];
#pragma unroll
    for (int i = 0; i < 32; i++) {
      gir += x[i] * swih[o * 32 + i];
      ghr += hd[i] * swhh[o * 32 + i];
      giz += x[i] * swih[(32 + o) * 32 + i];
      ghz += hd[i] * swhh[(32 + o) * 32 + i];
      gin += x[i] * swih[(64 + o) * 32 + i];
      ghn += hd[i] * swhh[(64 + o) * 32 + i];
    }
    float r = 1.f / (1.f + __expf(-(gir + ghr)));
    float z = 1.f / (1.f + __expf(-(giz + ghz)));
    float ng = tanhf(gin + r * ghn);
    out[o] = (1.f - z) * ng + z * hd[o];
  }
#pragma unroll
  for (int o = 0; o < 32; o++) hseq[(size_t)v * 32 + o] = out[o];
}

// ---------------- decoder: out = relu(h@dw1+db1)@dw2+db2  (V x 64) ---------
__global__ void k_dec(const float* __restrict__ hseq, const float* __restrict__ w1,
                      const float* __restrict__ b1, const float* __restrict__ w2,
                      const float* __restrict__ b2, float* __restrict__ out, int nV) {
  __shared__ float sw1[1024], sb1[32], sw2[2048], sb2[64];
  int t = threadIdx.x;
  for (int i = t; i < 1024; i += 256) sw1[i] = w1[i];
  for (int i = t; i < 2048; i += 256) sw2[i] = w2[i];
  if (t < 32) sb1[t] = b1[t];
  if (t < 64) sb2[t] = b2[t];
  __syncthreads();
  int v = blockIdx.x * 256 + t;
  if (v >= nV) return;
  float hx[32], t1[32];
#pragma unroll
  for (int i = 0; i < 32; i++) hx[i] = hseq[(size_t)v * 32 + i];
#pragma unroll
  for (int j = 0; j < 32; j++) {
    float s = sb1[j];
#pragma unroll
    for (int i = 0; i < 32; i++) s += hx[i] * sw1[i * 32 + j];
    t1[j] = fmaxf(s, 0.f);
  }
#pragma unroll 8
  for (int j = 0; j < 64; j++) {
    float s = sb2[j];
#pragma unroll
    for (int i = 0; i < 32; i++) s += t1[i] * sw2[i * 64 + j];
    out[(size_t)v * 64 + j] = s;
  }
}

extern "C" void kernel_launch(void* const* d_in, const int* in_sizes, int n_in,
                              void* d_out, int out_size, void* d_ws, size_t ws_size,
                              hipStream_t stream) {
  const float* node_feats = (const float*)d_in[0];
  const float* edge_feats = (const float*)d_in[1];
  const int* src = (const int*)d_in[2];
  const int* dst = (const int*)d_in[3];
  const float* proj_w1 = (const float*)d_in[4];
  const float* proj_b1 = (const float*)d_in[5];
  const float* proj_w2 = (const float*)d_in[6];
  const float* proj_b2 = (const float*)d_in[7];
  const float* e_w1 = (const float*)d_in[8];
  const float* e_b1 = (const float*)d_in[9];
  const float* e_w2 = (const float*)d_in[10];
  const float* e_b2 = (const float*)d_in[11];
  const float* conv_bias = (const float*)d_in[12];
  const float* gru_wih = (const float*)d_in[13];
  const float* gru_whh = (const float*)d_in[14];
  const float* gru_bih = (const float*)d_in[15];
  const float* gru_bhh = (const float*)d_in[16];
  const float* dec_w1 = (const float*)d_in[17];
  const float* dec_b1 = (const float*)d_in[18];
  const float* dec_w2 = (const float*)d_in[19];
  const float* dec_b2 = (const float*)d_in[20];
  float* out = (float*)d_out;

  const int nV = in_sizes[0] / 32;
  const int nE = in_sizes[2];

  // workspace carve-up (~107 MB total; proven-safe budget is >=208 MB)
  char* base = (char*)d_ws;
  size_t off = 0;
  auto carve = [&](size_t bytes) {
    void* r = base + off;
    off = (off + bytes + 255) & ~(size_t)255;
    return r;
  };
  float* a = (float*)carve((size_t)nE * 128 * 4);
  float* hseq = (float*)carve((size_t)nV * 32 * 4);
  float* agg = (float*)carve((size_t)nV * 32 * 4);
  int* counts = (int*)carve((size_t)nV * 4);
  int* row_ptr = (int*)carve((size_t)(nV + 1) * 4);
  int* cursor = (int*)carve((size_t)nV * 4);
  int* perm = (int*)carve((size_t)nE * 4);
  (void)ws_size;

  const int TB = 256;
  int gV = (nV + TB - 1) / TB;
  int gE = (nE + TB - 1) / TB;
  int nGrp = (nV + NB - 1) / NB;

  // setup
  k_proj<<<gV, TB, 0, stream>>>(node_feats, proj_w1, proj_b1, proj_w2, proj_b2, hseq, nV);
  k_edgeh<<<(nE + 1) / 2, TB, 0, stream>>>(edge_feats, e_w1, e_b1, a, nE);
  hipMemsetAsync(counts, 0, (size_t)nV * 4, stream);
  k_count<<<gE, TB, 0, stream>>>(src, counts, nE);
  k_scan<<<1, 1024, 0, stream>>>(counts, row_ptr, nV);
  k_copy<<<gV, TB, 0, stream>>>(row_ptr, cursor, nV);
  k_scatter<<<gE, TB, 0, stream>>>(src, cursor, perm, nE);

  // 6 message-passing steps
  for (int step = 0; step < 6; step++) {
    hipMemsetAsync(agg, 0, (size_t)nV * 32 * 4, stream);
    k_step<<<nGrp * 4, TB, 0, stream>>>(hseq, e_w2, e_b2, a, row_ptr, perm, dst, agg, nV);
    k_gru<<<gV, TB, 0, stream>>>(agg, conv_bias, gru_wih, gru_whh, gru_bih, gru_bhh, hseq, nV);
  }

  // decoder
  k_dec<<<gV, TB, 0, stream>>>(hseq, dec_w1, dec_b1, dec_w2, dec_b2, out, nV);
}

// Round 4
// 1663.975 us; speedup vs baseline: 1.5641x; 1.5641x over previous
//
#include <hip/hip_runtime.h>
#include <hip/hip_bf16.h>

// MPNN GNN: V=12500 nodes (feat 32), E=200000 edges (feat 16), H=32, 6 steps.
// Factorization: W_e = relu(ef@e_w1)@e_w2 + e_b2 is rank-128:
//   msg[e,o] = sum_k a[e,k]*T[src[e],k,o] + Tb[src[e],o]
//   a  = relu(ef@e_w1+e_b1)                (E x 128, loop-invariant, f32)
//   T  = per-step, computed in LDS per src-group (never in HBM)
//   Tb = h @ e_b2-reshaped
// R3 lessons: k_gru at 49 blocks was occupancy-starved (225us ea); 25.6M
// atomics/step in k_step. R4: atomic-free via per-edge partial buffer msgi
// [e][kc][o] + dst-CSR gather fused into the GRU kernel; (node,out)-parallel
// MLP kernels.

#define NB 8  // src nodes per k_step block

// ---------------- node projection: h = relu(nf@w1+b1)@w2+b2 ----------------
// block = 8 nodes x 32 outputs
__global__ __launch_bounds__(256) void k_proj(
    const float* __restrict__ nf, const float* __restrict__ w1,
    const float* __restrict__ b1, const float* __restrict__ w2,
    const float* __restrict__ b2, float* __restrict__ hseq, int nV) {
  __shared__ float sw1[1024], sw2[1024], sb1[32], sb2[32];
  __shared__ float sx[8][32], st1[8][32];
  int t = threadIdx.x;
  int v0 = blockIdx.x * 8;
  for (int i = t; i < 1024; i += 256) { sw1[i] = w1[i]; sw2[i] = w2[i]; }
  if (t < 32) { sb1[t] = b1[t]; sb2[t] = b2[t]; }
  {
    int g = v0 * 32 + t;
    sx[t >> 5][t & 31] = (g < nV * 32) ? nf[g] : 0.f;
  }
  __syncthreads();
  int n = t >> 5, j = t & 31;
  float s = sb1[j];
#pragma unroll
  for (int i = 0; i < 32; i++) s += sx[n][i] * sw1[i * 32 + j];
  st1[n][j] = fmaxf(s, 0.f);
  __syncthreads();
  float h = sb2[j];
#pragma unroll
  for (int i = 0; i < 32; i++) h += st1[n][i] * sw2[i * 32 + j];
  if (v0 + n < nV) hseq[(size_t)(v0 + n) * 32 + j] = h;
}

// ---------------- edge hidden: a = relu(ef@e_w1+e_b1), (E x 128) f32 -------
__global__ __launch_bounds__(256) void k_edgeh(
    const float* __restrict__ ef, const float* __restrict__ w1,
    const float* __restrict__ b1, float* __restrict__ a, int nE) {
  __shared__ float sw1[16 * 128], sb1[128], sef[2 * 16];
  int t = threadIdx.x;
  for (int i = t; i < 2048; i += 256) sw1[i] = w1[i];
  if (t < 128) sb1[t] = b1[t];
  int e0 = blockIdx.x * 2;
  if (t < 32) {
    int e = e0 + (t >> 4);
    if (e < nE) sef[t] = ef[(size_t)e * 16 + (t & 15)];
  }
  __syncthreads();
  int el = t >> 7, c = t & 127;
  int e = e0 + el;
  if (e >= nE) return;
  float s = sb1[c];
#pragma unroll
  for (int i = 0; i < 16; i++) s += sef[el * 16 + i] * sw1[i * 128 + c];
  a[(size_t)e * 128 + c] = fmaxf(s, 0.f);
}

// ---------------- CSR build (used for both src and dst keys) ---------------
__global__ __launch_bounds__(256) void k_count(const int* __restrict__ key,
                                               int* __restrict__ counts, int nE) {
  int e = blockIdx.x * 256 + threadIdx.x;
  if (e < nE) atomicAdd(&counts[key[e]], 1);
}

__global__ __launch_bounds__(1024) void k_scan(const int* __restrict__ counts,
                                               int* __restrict__ row_ptr, int nV) {
  __shared__ int buf[1024];
  __shared__ int s_off;
  int t = threadIdx.x;
  if (t == 0) s_off = 0;
  __syncthreads();
  for (int base = 0; base < nV; base += 1024) {
    int x = (base + t < nV) ? counts[base + t] : 0;
    buf[t] = x;
    __syncthreads();
    for (int d = 1; d < 1024; d <<= 1) {
      int v2 = (t >= d) ? buf[t - d] : 0;
      __syncthreads();
      buf[t] += v2;
      __syncthreads();
    }
    int incl = buf[t];
    int off = s_off;
    __syncthreads();
    if (base + t < nV) row_ptr[base + t] = off + incl - x;  // exclusive
    if (t == 1023) s_off = off + incl;
    __syncthreads();
  }
  if (t == 0) row_ptr[nV] = s_off;
}

__global__ __launch_bounds__(256) void k_copy(const int* __restrict__ row_ptr,
                                              int* __restrict__ cursor, int nV) {
  int v = blockIdx.x * 256 + threadIdx.x;
  if (v < nV) cursor[v] = row_ptr[v];
}

__global__ __launch_bounds__(256) void k_scatter(const int* __restrict__ key,
                                                 int* __restrict__ cursor,
                                                 int* __restrict__ perm, int nE) {
  int e = blockIdx.x * 256 + threadIdx.x;
  if (e < nE) {
    int p = atomicAdd(&cursor[key[e]], 1);
    perm[p] = e;
  }
}

// ---------------- per-step: T-in-LDS + per-edge partial messages -----------
// Block = (group of NB src nodes) x (k-chunk kc of 32 of 128). grid = nGrp*4.
// Writes msgi[e*128 + kc*32 + o] (each cell owned by exactly one thread).
__global__ __launch_bounds__(256) void k_step(
    const float* __restrict__ hseq, const float* __restrict__ w2,
    const float* __restrict__ b2, const float* __restrict__ a,
    const int* __restrict__ row_ptr, const int* __restrict__ perm,
    float* __restrict__ msgi, int nV) {
  __shared__ float sT[NB * 1024];  // [n][k][o], o fastest
  __shared__ float sh[NB][32];
  __shared__ float sTb[NB][32];
  __shared__ int s_rp[NB + 1];
  int t = threadIdx.x;
  int grp = blockIdx.x >> 2;
  int kc = blockIdx.x & 3;
  int v0 = grp * NB;
  if (t <= NB) {
    int v = v0 + t;
    if (v > nV) v = nV;
    s_rp[t] = row_ptr[v];
  }
  for (int i = t; i < NB * 32; i += 256) {
    int n = i >> 5, v = v0 + n;
    sh[n][i & 31] = (v < nV) ? hseq[(size_t)v * 32 + (i & 31)] : 0.f;
  }
  __syncthreads();
  if (s_rp[0] == s_rp[NB]) return;  // group has no out-edges (block-uniform)

  // T subtile: k in [kc*32, kc*32+32), all NB nodes
  for (int idx = t; idx < 1024; idx += 256) {
    int k = idx >> 5, o = idx & 31;
    const float* w = w2 + (size_t)(kc * 32 + k) * 1024 + o;  // + i*32
    float acc[NB];
#pragma unroll
    for (int n = 0; n < NB; n++) acc[n] = 0.f;
#pragma unroll 8
    for (int i = 0; i < 32; i++) {
      float wv = w[i * 32];
#pragma unroll
      for (int n = 0; n < NB; n++) acc[n] += sh[n][i] * wv;
    }
#pragma unroll
    for (int n = 0; n < NB; n++) sT[(n << 10) + idx] = acc[n];
  }
  // Tb (edge-MLP bias term), contributed once via the kc==0 partial
  if (kc == 0) {
    for (int idx = t; idx < NB * 32; idx += 256) {
      int n = idx >> 5, o = idx & 31;
      float s = 0.f;
#pragma unroll
      for (int i = 0; i < 32; i++) s += sh[n][i] * b2[i * 32 + o];
      sTb[n][o] = s;
    }
  }
  __syncthreads();

  int lane_o = t & 31, sub = t >> 5;  // 8 edge slots x 32 output lanes
  int beg = s_rp[0], end = s_rp[NB];
  int n = 0;
  for (int idx = beg + sub; idx < end; idx += 8) {
    while (idx >= s_rp[n + 1]) n++;  // monotonic across iterations
    int e = perm[idx];
    const float4* a4 = (const float4*)(a + (size_t)e * 128 + kc * 32);
    float s = (kc == 0) ? sTb[n][lane_o] : 0.f;
    const float* Tn = sT + (n << 10) + lane_o;
#pragma unroll
    for (int kq = 0; kq < 8; kq++) {
      float4 av = a4[kq];
      s += av.x * Tn[(kq * 4 + 0) << 5];
      s += av.y * Tn[(kq * 4 + 1) << 5];
      s += av.z * Tn[(kq * 4 + 2) << 5];
      s += av.w * Tn[(kq * 4 + 3) << 5];
    }
    msgi[(size_t)e * 128 + kc * 32 + lane_o] = s;
  }
}

// ---------------- fused dst-gather + GRU: block = 8 dst nodes x 32 o -------
__global__ __launch_bounds__(256) void k_agru(
    const float* __restrict__ msgi, const int* __restrict__ rpD,
    const int* __restrict__ permD, const float* __restrict__ cbias,
    const float* __restrict__ wih, const float* __restrict__ whh,
    const float* __restrict__ bih, const float* __restrict__ bhh,
    float* __restrict__ hseq, int nV) {
  __shared__ float swT[2][32 * 97];  // transposed, stride-97 pad: [w][i*97+row]
  __shared__ float sb[2][96], scb[32];
  __shared__ float sx[8][32], shd[8][32];
  __shared__ int srp[9];
  int t = threadIdx.x;
  int v0 = blockIdx.x * 8;
  for (int idx = t; idx < 3072; idx += 256) {
    int row = idx >> 5, i = idx & 31;
    swT[0][i * 97 + row] = wih[idx];
    swT[1][i * 97 + row] = whh[idx];
  }
  if (t < 96) { sb[0][t] = bih[t]; sb[1][t] = bhh[t]; }
  if (t < 32) scb[t] = cbias[t];
  if (t <= 8) {
    int v = v0 + t;
    if (v > nV) v = nV;
    srp[t] = rpD[v];
  }
  {
    int n = t >> 5, v = v0 + n;
    shd[n][t & 31] = (v < nV) ? hseq[(size_t)v * 32 + (t & 31)] : 0.f;
  }
  __syncthreads();
  int n = t >> 5, o = t & 31;
  // gather: sum the 4 kc-partials over this node's in-edges
  float s = 0.f;
  for (int idx = srp[n]; idx < srp[n + 1]; ++idx) {
    int e = permD[idx];
    const float* m = msgi + (size_t)e * 128;
    s += (m[o] + m[32 + o]) + (m[64 + o] + m[96 + o]);
  }
  sx[n][o] = fmaxf(s + scb[o], 0.f);
  __syncthreads();
  int v = v0 + n;
  if (v >= nV) return;
  float gir = sb[0][o], giz = sb[0][32 + o], gin = sb[0][64 + o];
  float ghr = sb[1][o], ghz = sb[1][32 + o], ghn = sb[1][64 + o];
#pragma unroll
  for (int i = 0; i < 32; i++) {
    float xi = sx[n][i], hi = shd[n][i];
    gir += xi * swT[0][i * 97 + o];
    giz += xi * swT[0][i * 97 + 32 + o];
    gin += xi * swT[0][i * 97 + 64 + o];
    ghr += hi * swT[1][i * 97 + o];
    ghz += hi * swT[1][i * 97 + 32 + o];
    ghn += hi * swT[1][i * 97 + 64 + o];
  }
  float r = 1.f / (1.f + __expf(-(gir + ghr)));
  float z = 1.f / (1.f + __expf(-(giz + ghz)));
  float ng = tanhf(gin + r * ghn);
  hseq[(size_t)v * 32 + o] = (1.f - z) * ng + z * shd[n][o];
}

// ---------------- decoder: out = relu(h@dw1+db1)@dw2+db2  (V x 64) ---------
// block = 4 nodes; phase1 4x32 threads, phase2 4x64 threads
__global__ __launch_bounds__(256) void k_dec(
    const float* __restrict__ hseq, const float* __restrict__ w1,
    const float* __restrict__ b1, const float* __restrict__ w2,
    const float* __restrict__ b2, float* __restrict__ out, int nV) {
  __shared__ float sw1[1024], sb1[32], sw2[2048], sb2[64];
  __shared__ float sx[4][32], st1[4][32];
  int t = threadIdx.x;
  int v0 = blockIdx.x * 4;
  for (int i = t; i < 1024; i += 256) sw1[i] = w1[i];
  for (int i = t; i < 2048; i += 256) sw2[i] = w2[i];
  if (t < 32) sb1[t] = b1[t];
  if (t < 64) sb2[t] = b2[t];
  if (t < 128) {
    int g = v0 * 32 + t;
    sx[t >> 5][t & 31] = (g < nV * 32) ? hseq[g] : 0.f;
  }
  __syncthreads();
  if (t < 128) {
    int n = t >> 5, j = t & 31;
    float s = sb1[j];
#pragma unroll
    for (int i = 0; i < 32; i++) s += sx[n][i] * sw1[i * 32 + j];
    st1[n][j] = fmaxf(s, 0.f);
  }
  __syncthreads();
  int n = t >> 6, j = t & 63;
  float s = sb2[j];
#pragma unroll
  for (int i = 0; i < 32; i++) s += st1[n][i] * sw2[i * 64 + j];
  if (v0 + n < nV) out[(size_t)(v0 + n) * 64 + j] = s;
}

extern "C" void kernel_launch(void* const* d_in, const int* in_sizes, int n_in,
                              void* d_out, int out_size, void* d_ws, size_t ws_size,
                              hipStream_t stream) {
  const float* node_feats = (const float*)d_in[0];
  const float* edge_feats = (const float*)d_in[1];
  const int* src = (const int*)d_in[2];
  const int* dst = (const int*)d_in[3];
  const float* proj_w1 = (const float*)d_in[4];
  const float* proj_b1 = (const float*)d_in[5];
  const float* proj_w2 = (const float*)d_in[6];
  const float* proj_b2 = (const float*)d_in[7];
  const float* e_w1 = (const float*)d_in[8];
  const float* e_b1 = (const float*)d_in[9];
  const float* e_w2 = (const float*)d_in[10];
  const float* e_b2 = (const float*)d_in[11];
  const float* conv_bias = (const float*)d_in[12];
  const float* gru_wih = (const float*)d_in[13];
  const float* gru_whh = (const float*)d_in[14];
  const float* gru_bih = (const float*)d_in[15];
  const float* gru_bhh = (const float*)d_in[16];
  const float* dec_w1 = (const float*)d_in[17];
  const float* dec_b1 = (const float*)d_in[18];
  const float* dec_w2 = (const float*)d_in[19];
  const float* dec_b2 = (const float*)d_in[20];
  float* out = (float*)d_out;

  const int nV = in_sizes[0] / 32;
  const int nE = in_sizes[2];

  // workspace carve-up (~208 MB; proven-safe budget >= 211 MB, crash at 313)
  char* base = (char*)d_ws;
  size_t off = 0;
  auto carve = [&](size_t bytes) {
    void* r = base + off;
    off = (off + bytes + 255) & ~(size_t)255;
    return r;
  };
  float* a = (float*)carve((size_t)nE * 128 * 4);
  float* msgi = (float*)carve((size_t)nE * 128 * 4);
  float* hseq = (float*)carve((size_t)nV * 32 * 4);
  int* countsS = (int*)carve((size_t)nV * 4);
  int* rpS = (int*)carve((size_t)(nV + 1) * 4);
  int* curS = (int*)carve((size_t)nV * 4);
  int* permS = (int*)carve((size_t)nE * 4);
  int* countsD = (int*)carve((size_t)nV * 4);
  int* rpD = (int*)carve((size_t)(nV + 1) * 4);
  int* curD = (int*)carve((size_t)nV * 4);
  int* permD = (int*)carve((size_t)nE * 4);
  (void)ws_size;

  const int TB = 256;
  int gE = (nE + TB - 1) / TB;
  int g8 = (nV + 7) / 8;
  int g4 = (nV + 3) / 4;

  // setup
  k_proj<<<g8, TB, 0, stream>>>(node_feats, proj_w1, proj_b1, proj_w2, proj_b2, hseq, nV);
  k_edgeh<<<(nE + 1) / 2, TB, 0, stream>>>(edge_feats, e_w1, e_b1, a, nE);
  hipMemsetAsync(countsS, 0, (size_t)nV * 4, stream);
  hipMemsetAsync(countsD, 0, (size_t)nV * 4, stream);
  k_count<<<gE, TB, 0, stream>>>(src, countsS, nE);
  k_count<<<gE, TB, 0, stream>>>(dst, countsD, nE);
  k_scan<<<1, 1024, 0, stream>>>(countsS, rpS, nV);
  k_scan<<<1, 1024, 0, stream>>>(countsD, rpD, nV);
  k_copy<<<(nV + TB - 1) / TB, TB, 0, stream>>>(rpS, curS, nV);
  k_copy<<<(nV + TB - 1) / TB, TB, 0, stream>>>(rpD, curD, nV);
  k_scatter<<<gE, TB, 0, stream>>>(src, curS, permS, nE);
  k_scatter<<<gE, TB, 0, stream>>>(dst, curD, permD, nE);

  // 6 message-passing steps (atomic-free)
  for (int step = 0; step < 6; step++) {
    k_step<<<g8 * 4, TB, 0, stream>>>(hseq, e_w2, e_b2, a, rpS, permS, msgi, nV);
    k_agru<<<g8, TB, 0, stream>>>(msgi, rpD, permD, conv_bias, gru_wih, gru_whh,
                                  gru_bih, gru_bhh, hseq, nV);
  }

  // decoder
  k_dec<<<g4, TB, 0, stream>>>(hseq, dec_w1, dec_b1, dec_w2, dec_b2, out, nV);
}

// Round 5
// 1412.293 us; speedup vs baseline: 1.8428x; 1.1782x over previous
//
#include <hip/hip_runtime.h>
#include <hip/hip_bf16.h>

// MPNN GNN: V=12500 (feat 32), E=200000 (feat 16), H=32, 6 steps.
// Factorization: W_e = relu(ef@e_w1)@e_w2 + e_b2 is rank-128:
//   msg[e,o] = sum_k a[e,k]*T[src[e],k,o] + Tb[src[e],o]
//   a  = relu(ef@e_w1+e_b1)   (E x 128, loop-invariant, f32, 102 MB)
//   T  = per-step per-src-group tile in LDS (never in HBM)
// History: R3 atomics ~120us/step; R4 msgi buffer -> 1.2GB/step HBM (196us/step).
// R5: atomics into L2-resident agg (1.6 MB) + transposed+swizzled LDS T tile
// ([n][o][k], 16B-granule XOR by (o&7)) so the edge loop reads ds_read_b128.

#define NB 8  // src nodes per k_step block

// ---------------- node projection: h = relu(nf@w1+b1)@w2+b2 ----------------
__global__ __launch_bounds__(256) void k_proj(
    const float* __restrict__ nf, const float* __restrict__ w1,
    const float* __restrict__ b1, const float* __restrict__ w2,
    const float* __restrict__ b2, float* __restrict__ hseq, int nV) {
  __shared__ float sw1[1024], sw2[1024], sb1[32], sb2[32];
  __shared__ float sx[8][32], st1[8][32];
  int t = threadIdx.x;
  int v0 = blockIdx.x * 8;
  for (int i = t; i < 1024; i += 256) { sw1[i] = w1[i]; sw2[i] = w2[i]; }
  if (t < 32) { sb1[t] = b1[t]; sb2[t] = b2[t]; }
  {
    int g = v0 * 32 + t;
    sx[t >> 5][t & 31] = (g < nV * 32) ? nf[g] : 0.f;
  }
  __syncthreads();
  int n = t >> 5, j = t & 31;
  float s = sb1[j];
#pragma unroll
  for (int i = 0; i < 32; i++) s += sx[n][i] * sw1[i * 32 + j];
  st1[n][j] = fmaxf(s, 0.f);
  __syncthreads();
  float h = sb2[j];
#pragma unroll
  for (int i = 0; i < 32; i++) h += st1[n][i] * sw2[i * 32 + j];
  if (v0 + n < nV) hseq[(size_t)(v0 + n) * 32 + j] = h;
}

// ---------------- edge hidden: a = relu(ef@e_w1+e_b1), (E x 128) f32 -------
__global__ __launch_bounds__(256) void k_edgeh(
    const float* __restrict__ ef, const float* __restrict__ w1,
    const float* __restrict__ b1, float* __restrict__ a, int nE) {
  __shared__ float sw1[16 * 128], sb1[128], sef[2 * 16];
  int t = threadIdx.x;
  for (int i = t; i < 2048; i += 256) sw1[i] = w1[i];
  if (t < 128) sb1[t] = b1[t];
  int e0 = blockIdx.x * 2;
  if (t < 32) {
    int e = e0 + (t >> 4);
    if (e < nE) sef[t] = ef[(size_t)e * 16 + (t & 15)];
  }
  __syncthreads();
  int el = t >> 7, c = t & 127;
  int e = e0 + el;
  if (e >= nE) return;
  float s = sb1[c];
#pragma unroll
  for (int i = 0; i < 16; i++) s += sef[el * 16 + i] * sw1[i * 128 + c];
  a[(size_t)e * 128 + c] = fmaxf(s, 0.f);
}

// ---------------- CSR by src ----------------
__global__ __launch_bounds__(256) void k_count(const int* __restrict__ key,
                                               int* __restrict__ counts, int nE) {
  int e = blockIdx.x * 256 + threadIdx.x;
  if (e < nE) atomicAdd(&counts[key[e]], 1);
}

__global__ __launch_bounds__(1024) void k_scan(const int* __restrict__ counts,
                                               int* __restrict__ row_ptr, int nV) {
  __shared__ int buf[1024];
  __shared__ int s_off;
  int t = threadIdx.x;
  if (t == 0) s_off = 0;
  __syncthreads();
  for (int base = 0; base < nV; base += 1024) {
    int x = (base + t < nV) ? counts[base + t] : 0;
    buf[t] = x;
    __syncthreads();
    for (int d = 1; d < 1024; d <<= 1) {
      int v2 = (t >= d) ? buf[t - d] : 0;
      __syncthreads();
      buf[t] += v2;
      __syncthreads();
    }
    int incl = buf[t];
    int off = s_off;
    __syncthreads();
    if (base + t < nV) row_ptr[base + t] = off + incl - x;  // exclusive
    if (t == 1023) s_off = off + incl;
    __syncthreads();
  }
  if (t == 0) row_ptr[nV] = s_off;
}

__global__ __launch_bounds__(256) void k_copy(const int* __restrict__ row_ptr,
                                              int* __restrict__ cursor, int nV) {
  int v = blockIdx.x * 256 + threadIdx.x;
  if (v < nV) cursor[v] = row_ptr[v];
}

__global__ __launch_bounds__(256) void k_scatter(const int* __restrict__ key,
                                                 int* __restrict__ cursor,
                                                 int* __restrict__ perm, int nE) {
  int e = blockIdx.x * 256 + threadIdx.x;
  if (e < nE) {
    int p = atomicAdd(&cursor[key[e]], 1);
    perm[p] = e;
  }
}

// ---------------- per-step: T-in-LDS + message + atomic scatter ------------
// Block = (group of NB src nodes) x (k-chunk kc of 32 of 128). grid = nGrp*4.
// LDS T tile TRANSPOSED [n][o][k], 16B granules XOR-swizzled by (o&7):
//   float index: n*1024 + o*32 + ((kl>>2)^(o&7))*4 + (kl&3)
// -> edge loop reads 8x ds_read_b128 per edge (lanes o=0..7 span all banks).
__global__ __launch_bounds__(256) void k_step(
    const float* __restrict__ hseq, const float* __restrict__ w2,
    const float* __restrict__ b2, const float* __restrict__ a,
    const int* __restrict__ row_ptr, const int* __restrict__ perm,
    const int* __restrict__ dst, float* __restrict__ agg, int nV) {
  __shared__ float sT[NB * 1024];
  __shared__ float sh[NB][32];
  __shared__ float sTb[NB][32];
  __shared__ int s_rp[NB + 1];
  int t = threadIdx.x;
  int grp = blockIdx.x >> 2;
  int kc = blockIdx.x & 3;
  int v0 = grp * NB;
  if (t <= NB) {
    int v = v0 + t;
    if (v > nV) v = nV;
    s_rp[t] = row_ptr[v];
  }
  for (int i = t; i < NB * 32; i += 256) {
    int n = i >> 5, v = v0 + n;
    sh[n][i & 31] = (v < nV) ? hseq[(size_t)v * 32 + (i & 31)] : 0.f;
  }
  __syncthreads();
  if (s_rp[0] == s_rp[NB]) return;  // group has no out-edges (block-uniform)

  // T subtile: local kl in [0,32) -> global k = kc*32+kl, all NB nodes.
  for (int idx = t; idx < 1024; idx += 256) {
    int kl = idx >> 5, o = idx & 31;
    const float* w = w2 + (size_t)(kc * 32 + kl) * 1024 + o;  // + i*32
    float acc[NB];
#pragma unroll
    for (int n = 0; n < NB; n++) acc[n] = 0.f;
#pragma unroll 8
    for (int i = 0; i < 32; i++) {
      float wv = w[i * 32];
#pragma unroll
      for (int n = 0; n < NB; n++) acc[n] += sh[n][i] * wv;
    }
    int soff = (o << 5) + (((kl >> 2) ^ (o & 7)) << 2) + (kl & 3);
#pragma unroll
    for (int n = 0; n < NB; n++) sT[(n << 10) + soff] = acc[n];
  }
  // Tb (edge-MLP bias term), contributed once via the kc==0 blocks
  if (kc == 0) {
    for (int idx = t; idx < NB * 32; idx += 256) {
      int n = idx >> 5, o = idx & 31;
      float s = 0.f;
#pragma unroll
      for (int i = 0; i < 32; i++) s += sh[n][i] * b2[i * 32 + o];
      sTb[n][o] = s;
    }
  }
  __syncthreads();

  int o = t & 31, sub = t >> 5;  // 8 edge slots x 32 output lanes
  int ox = o & 7;
  int beg = s_rp[0], end = s_rp[NB];
  const float4* sT4 = (const float4*)sT;
  int n = 0;
  for (int idx = beg + sub; idx < end; idx += 8) {
    while (idx >= s_rp[n + 1]) n++;  // monotonic across iterations
    int e = perm[idx];
    const float4* a4 = (const float4*)(a + (size_t)e * 128 + kc * 32);
    float s = (kc == 0) ? sTb[n][o] : 0.f;
    const float4* Tn4 = sT4 + (n << 8) + (o << 3);
#pragma unroll
    for (int g = 0; g < 8; g++) {
      float4 av = a4[g];
      float4 tv = Tn4[g ^ ox];
      s += av.x * tv.x + av.y * tv.y + av.z * tv.z + av.w * tv.w;
    }
    atomicAdd(&agg[(size_t)dst[e] * 32 + o], s);
  }
}

// ---------------- fused agg-read + GRU: block = 8 nodes x 32 o -------------
__global__ __launch_bounds__(256) void k_agru(
    const float* __restrict__ agg, const float* __restrict__ cbias,
    const float* __restrict__ wih, const float* __restrict__ whh,
    const float* __restrict__ bih, const float* __restrict__ bhh,
    float* __restrict__ hseq, int nV) {
  __shared__ float swT[2][32 * 97];  // transposed, stride-97 pad
  __shared__ float sb[2][96], scb[32];
  __shared__ float sx[8][32], shd[8][32];
  int t = threadIdx.x;
  int v0 = blockIdx.x * 8;
  for (int idx = t; idx < 3072; idx += 256) {
    int row = idx >> 5, i = idx & 31;
    swT[0][i * 97 + row] = wih[idx];
    swT[1][i * 97 + row] = whh[idx];
  }
  if (t < 96) { sb[0][t] = bih[t]; sb[1][t] = bhh[t]; }
  if (t < 32) scb[t] = cbias[t];
  {
    int n = t >> 5, v = v0 + n, j = t & 31;
    shd[n][j] = (v < nV) ? hseq[(size_t)v * 32 + j] : 0.f;
    sx[n][j] = (v < nV) ? fmaxf(agg[(size_t)v * 32 + j] + cbias[j], 0.f) : 0.f;
  }
  __syncthreads();
  int n = t >> 5, o = t & 31;
  int v = v0 + n;
  if (v >= nV) return;
  float gir = sb[0][o], giz = sb[0][32 + o], gin = sb[0][64 + o];
  float ghr = sb[1][o], ghz = sb[1][32 + o], ghn = sb[1][64 + o];
#pragma unroll
  for (int i = 0; i < 32; i++) {
    float xi = sx[n][i], hi = shd[n][i];
    gir += xi * swT[0][i * 97 + o];
    giz += xi * swT[0][i * 97 + 32 + o];
    gin += xi * swT[0][i * 97 + 64 + o];
    ghr += hi * swT[1][i * 97 + o];
    ghz += hi * swT[1][i * 97 + 32 + o];
    ghn += hi * swT[1][i * 97 + 64 + o];
  }
  float r = 1.f / (1.f + __expf(-(gir + ghr)));
  float z = 1.f / (1.f + __expf(-(giz + ghz)));
  float ng = tanhf(gin + r * ghn);
  hseq[(size_t)v * 32 + o] = (1.f - z) * ng + z * shd[n][o];
}

// ---------------- decoder: out = relu(h@dw1+db1)@dw2+db2  (V x 64) ---------
__global__ __launch_bounds__(256) void k_dec(
    const float* __restrict__ hseq, const float* __restrict__ w1,
    const float* __restrict__ b1, const float* __restrict__ w2,
    const float* __restrict__ b2, float* __restrict__ out, int nV) {
  __shared__ float sw1[1024], sb1[32], sw2[2048], sb2[64];
  __shared__ float sx[4][32], st1[4][32];
  int t = threadIdx.x;
  int v0 = blockIdx.x * 4;
  for (int i = t; i < 1024; i += 256) sw1[i] = w1[i];
  for (int i = t; i < 2048; i += 256) sw2[i] = w2[i];
  if (t < 32) sb1[t] = b1[t];
  if (t < 64) sb2[t] = b2[t];
  if (t < 128) {
    int g = v0 * 32 + t;
    sx[t >> 5][t & 31] = (g < nV * 32) ? hseq[g] : 0.f;
  }
  __syncthreads();
  if (t < 128) {
    int n = t >> 5, j = t & 31;
    float s = sb1[j];
#pragma unroll
    for (int i = 0; i < 32; i++) s += sx[n][i] * sw1[i * 32 + j];
    st1[n][j] = fmaxf(s, 0.f);
  }
  __syncthreads();
  int n = t >> 6, j = t & 63;
  float s = sb2[j];
#pragma unroll
  for (int i = 0; i < 32; i++) s += st1[n][i] * sw2[i * 64 + j];
  if (v0 + n < nV) out[(size_t)(v0 + n) * 64 + j] = s;
}

extern "C" void kernel_launch(void* const* d_in, const int* in_sizes, int n_in,
                              void* d_out, int out_size, void* d_ws, size_t ws_size,
                              hipStream_t stream) {
  const float* node_feats = (const float*)d_in[0];
  const float* edge_feats = (const float*)d_in[1];
  const int* src = (const int*)d_in[2];
  const int* dst = (const int*)d_in[3];
  const float* proj_w1 = (const float*)d_in[4];
  const float* proj_b1 = (const float*)d_in[5];
  const float* proj_w2 = (const float*)d_in[6];
  const float* proj_b2 = (const float*)d_in[7];
  const float* e_w1 = (const float*)d_in[8];
  const float* e_b1 = (const float*)d_in[9];
  const float* e_w2 = (const float*)d_in[10];
  const float* e_b2 = (const float*)d_in[11];
  const float* conv_bias = (const float*)d_in[12];
  const float* gru_wih = (const float*)d_in[13];
  const float* gru_whh = (const float*)d_in[14];
  const float* gru_bih = (const float*)d_in[15];
  const float* gru_bhh = (const float*)d_in[16];
  const float* dec_w1 = (const float*)d_in[17];
  const float* dec_b1 = (const float*)d_in[18];
  const float* dec_w2 = (const float*)d_in[19];
  const float* dec_b2 = (const float*)d_in[20];
  float* out = (float*)d_out;

  const int nV = in_sizes[0] / 32;
  const int nE = in_sizes[2];

  // workspace carve-up (~107 MB; known-safe)
  char* base = (char*)d_ws;
  size_t off = 0;
  auto carve = [&](size_t bytes) {
    void* r = base + off;
    off = (off + bytes + 255) & ~(size_t)255;
    return r;
  };
  float* a = (float*)carve((size_t)nE * 128 * 4);
  float* hseq = (float*)carve((size_t)nV * 32 * 4);
  float* agg = (float*)carve((size_t)nV * 32 * 4);
  int* countsS = (int*)carve((size_t)nV * 4);
  int* rpS = (int*)carve((size_t)(nV + 1) * 4);
  int* curS = (int*)carve((size_t)nV * 4);
  int* permS = (int*)carve((size_t)nE * 4);
  (void)ws_size;

  const int TB = 256;
  int gE = (nE + TB - 1) / TB;
  int g8 = (nV + 7) / 8;
  int g4 = (nV + 3) / 4;

  // setup
  k_proj<<<g8, TB, 0, stream>>>(node_feats, proj_w1, proj_b1, proj_w2, proj_b2, hseq, nV);
  k_edgeh<<<(nE + 1) / 2, TB, 0, stream>>>(edge_feats, e_w1, e_b1, a, nE);
  hipMemsetAsync(countsS, 0, (size_t)nV * 4, stream);
  k_count<<<gE, TB, 0, stream>>>(src, countsS, nE);
  k_scan<<<1, 1024, 0, stream>>>(countsS, rpS, nV);
  k_copy<<<(nV + TB - 1) / TB, TB, 0, stream>>>(rpS, curS, nV);
  k_scatter<<<gE, TB, 0, stream>>>(src, curS, permS, nE);

  // 6 message-passing steps (atomics into L2-resident agg)
  for (int step = 0; step < 6; step++) {
    hipMemsetAsync(agg, 0, (size_t)nV * 32 * 4, stream);
    k_step<<<g8 * 4, TB, 0, stream>>>(hseq, e_w2, e_b2, a, rpS, permS, dst, agg, nV);
    k_agru<<<g8, TB, 0, stream>>>(agg, conv_bias, gru_wih, gru_whh,
                                  gru_bih, gru_bhh, hseq, nV);
  }

  // decoder
  k_dec<<<g4, TB, 0, stream>>>(hseq, dec_w1, dec_b1, dec_w2, dec_b2, out, nV);
}